// Round 11
// baseline (175.195 us; speedup 1.0000x reference)
//
#include <hip/hip_runtime.h>
#include <math.h>

#define DIM 512
#define HID 8
#define LN_EPS 1e-5f

typedef float  f32x4 __attribute__((ext_vector_type(4)));
typedef __fp16 h16x2 __attribute__((ext_vector_type(2)));
typedef __fp16 h16x8 __attribute__((ext_vector_type(8)));

// ---- DPP cross-lane helpers ----
#define DPP_XOR1 0xB1   // quad_perm [1,0,3,2] : xor1
#define DPP_XOR2 0x4E   // quad_perm [2,3,0,1] : xor2
#define DPP_HM   0x141  // row_half_mirror: ==xor4 once 4-uniform
#define DPP_ROR8 0x128  // (i+8)&15 == i^8 : xor8 within 16

template <int CTRL>
__device__ __forceinline__ float dpp_movf(float v) {
    int r = __builtin_amdgcn_update_dpp(0, __builtin_bit_cast(int, v),
                                        CTRL, 0xF, 0xF, true);
    return __builtin_bit_cast(float, r);
}
template <int CTRL>
__device__ __forceinline__ float dpp_addf(float v) {
    return v + dpp_movf<CTRL>(v);
}
__device__ __forceinline__ float readlanef(float v, int lane) {
    return __builtin_bit_cast(float,
        __builtin_amdgcn_readlane(__builtin_bit_cast(int, v), lane));
}

// tanh-GELU via hardware exp2/rcp (abs err ~1e-3 vs exact; threshold 0.166)
__device__ __forceinline__ float gelu_fast(float v) {
    const float C = 0.044715f;
    const float K = 2.30258819f; // 2*0.7978845608*log2(e)
    float v2 = v * v;
    float t  = v * fmaf(C, v2, 1.0f);
    float e  = __builtin_amdgcn_exp2f(K * t);
    float r  = __builtin_amdgcn_rcpf(e + 1.0f);
    return fmaf(-v, r, v);
}

// full wave sum of a scalar (zero LDS)
__device__ __forceinline__ float wave_sum(float v) {
    v = dpp_addf<DPP_XOR1>(v);
    v = dpp_addf<DPP_XOR2>(v);
    v = dpp_addf<DPP_HM>(v);
    v = dpp_addf<DPP_ROR8>(v);
    return (readlanef(v, 0) + readlanef(v, 16))
         + (readlanef(v, 32) + readlanef(v, 48));
}

// reduce 8 partials; every lane ends with wave-complete sum of partial[lane&7]
__device__ __forceinline__ float reduce8(float ph[8], int lj) {
#pragma unroll
    for (int j = 0; j < 8; ++j) ph[j] = dpp_addf<DPP_XOR1>(ph[j]);
#pragma unroll
    for (int j = 0; j < 8; ++j) ph[j] = dpp_addf<DPP_XOR2>(ph[j]);
#pragma unroll
    for (int j = 0; j < 8; ++j) ph[j] = dpp_addf<DPP_HM>(ph[j]);
    float sel = ph[0];
    sel = (lj == 1) ? ph[1] : sel;
    sel = (lj == 2) ? ph[2] : sel;
    sel = (lj == 3) ? ph[3] : sel;
    sel = (lj == 4) ? ph[4] : sel;
    sel = (lj == 5) ? ph[5] : sel;
    sel = (lj == 6) ? ph[6] : sel;
    sel = (lj == 7) ? ph[7] : sel;
    sel = dpp_addf<DPP_ROR8>(sel);
    sel += __shfl_xor(sel, 16, 64);
    sel += __shfl_xor(sel, 32, 64);
    return sel;
}

__device__ __forceinline__ void load8(float* dst, const float* __restrict__ src) {
    const f32x4* p = reinterpret_cast<const f32x4*>(src);
    f32x4 a = p[0];
    f32x4 b = p[1];
    dst[0] = a.x; dst[1] = a.y; dst[2] = a.z; dst[3] = a.w;
    dst[4] = b.x; dst[5] = b.y; dst[6] = b.z; dst[7] = b.w;
}

// Weights in EXPLICIT LDS (fp16, LN-folded), shared block-wide; per-lane
// register state small. 2 rows per iteration: reduction trees interleave
// (latency hiding) and each weight ds_read feeds both rows.
__global__ __launch_bounds__(256)
void mlp_fused_kernel(const float* __restrict__ x,
                      const float* __restrict__ w1,
                      const float* __restrict__ b1,
                      const float* __restrict__ w2,
                      const float* __restrict__ b2,
                      const float* __restrict__ gamma,
                      const float* __restrict__ beta,
                      float* __restrict__ out,
                      int nrows, int rows_per_wave) {
    __shared__ __fp16 w1h[8 * DIM];    // [j][d] fp16, w1*gamma   (8 KB)
    __shared__ __fp16 w2h[DIM * HID];  // row-swizzled             (8 KB)

    const int tid  = threadIdx.x;
    const int lane = tid & 63;
    const int wav  = tid >> 6;
    const int lj   = lane & 7;
    const int dbase = lane * 8;

    // ================= staging (once per block) =================
    {
        const int j  = tid >> 5;
        const int d0 = (tid & 31) * 16;
        const float* wsrc = w1 + j * DIM + d0;
        const float* gsrc = gamma + d0;
        h16x8 p0, p1;
#pragma unroll
        for (int i = 0; i < 4; ++i) {
            float a = wsrc[2 * i]     * gsrc[2 * i];
            float b = wsrc[2 * i + 1] * gsrc[2 * i + 1];
            h16x2 p = __builtin_amdgcn_cvt_pkrtz(a, b);
            p0[2 * i] = p.x; p0[2 * i + 1] = p.y;
        }
#pragma unroll
        for (int i = 0; i < 4; ++i) {
            float a = wsrc[8 + 2 * i]     * gsrc[8 + 2 * i];
            float b = wsrc[8 + 2 * i + 1] * gsrc[8 + 2 * i + 1];
            h16x2 p = __builtin_amdgcn_cvt_pkrtz(a, b);
            p1[2 * i] = p.x; p1[2 * i + 1] = p.y;
        }
        *reinterpret_cast<h16x8*>(&w1h[j * DIM + d0])     = p0;
        *reinterpret_cast<h16x8*>(&w1h[j * DIM + d0 + 8]) = p1;

        // w2h: row d -> swizzled 16B-unit u(d) = (d>>3)*8 + ((d&7)^((d>>3)&7))
        // reader lane L, instr t reads unit L*8 + (t^(L&7)) == row L*8+t,
        // conflict-free across the wave.
#pragma unroll
        for (int rr = 0; rr < 2; ++rr) {
            const int d = tid + rr * 256;
            const float* src = w2 + (size_t)d * HID;
            f32x4 a = *reinterpret_cast<const f32x4*>(src);
            f32x4 b = *reinterpret_cast<const f32x4*>(src + 4);
            h16x8 pk;
            h16x2 q0 = __builtin_amdgcn_cvt_pkrtz(a.x, a.y);
            h16x2 q1 = __builtin_amdgcn_cvt_pkrtz(a.z, a.w);
            h16x2 q2 = __builtin_amdgcn_cvt_pkrtz(b.x, b.y);
            h16x2 q3 = __builtin_amdgcn_cvt_pkrtz(b.z, b.w);
            pk[0] = q0.x; pk[1] = q0.y; pk[2] = q1.x; pk[3] = q1.y;
            pk[4] = q2.x; pk[5] = q2.y; pk[6] = q3.x; pk[7] = q3.y;
            const int u = ((d >> 3) << 3) + ((d & 7) ^ ((d >> 3) & 7));
            *reinterpret_cast<h16x8*>(&w2h[u * 8]) = pk;
        }
    }
    __syncthreads();

    // ================= per-wave startup constants =================
    float w1sp[8];
#pragma unroll
    for (int j = 0; j < 8; ++j) {
        h16x8 wv = *reinterpret_cast<const h16x8*>(&w1h[j * DIM + dbase]);
        float a = 0.f;
#pragma unroll
        for (int i = 0; i < 8; ++i) a += (float)wv[i];
        w1sp[j] = a;
    }
    const float W1s = reduce8(w1sp, lj);   // Sum_d fp16(w1*gamma)[lj,d] (rounded)

    float bt[8];
    load8(bt, beta + dbase);
    float c1p[8];
#pragma unroll
    for (int j = 0; j < 8; ++j) {
        float raw[8];
        load8(raw, w1 + j * DIM + dbase);
        float a = 0.f;
#pragma unroll
        for (int k = 0; k < 8; ++k) a = fmaf(bt[k], raw[k], a);
        c1p[j] = a;
    }
    const float b1e = b1[lj] + reduce8(c1p, lj);

    float b2r[8];
    load8(b2r, b2 + dbase);

    // ================= row-pair loop =================
    const int wgid = blockIdx.x * 4 + wav;
    const int r0 = wgid * rows_per_wave;
    if (r0 >= nrows) return;
    int r1 = r0 + rows_per_wave;
    if (r1 > nrows) r1 = nrows;

    float xvA[8], xvB[8];
    load8(xvA, x + (size_t)r0 * DIM + dbase);
    {
        const int rb = (r0 + 1 < r1) ? r0 + 1 : r0;
        load8(xvB, x + (size_t)rb * DIM + dbase);
    }

    int r = r0;
    for (; r + 1 < r1; r += 2) {
        float xnA[8], xnB[8];
        const int ra2 = (r + 2 < r1) ? r + 2 : r1 - 1;
        const int rb2 = (r + 3 < r1) ? r + 3 : r1 - 1;
        load8(xnA, x + (size_t)ra2 * DIM + dbase);
        load8(xnB, x + (size_t)rb2 * DIM + dbase);

        // ---- LN stats ----
        float sA = 0.f, qA = 0.f, sB = 0.f, qB = 0.f;
#pragma unroll
        for (int k = 0; k < 8; ++k) {
            sA += xvA[k]; qA = fmaf(xvA[k], xvA[k], qA);
            sB += xvB[k]; qB = fmaf(xvB[k], xvB[k], qB);
        }

        // ---- pack x; stage-1 partials (one w1 ds_read feeds both rows) ----
        h16x2 xhA[4], xhB[4];
#pragma unroll
        for (int i = 0; i < 4; ++i) {
            xhA[i] = __builtin_amdgcn_cvt_pkrtz(xvA[2 * i], xvA[2 * i + 1]);
            xhB[i] = __builtin_amdgcn_cvt_pkrtz(xvB[2 * i], xvB[2 * i + 1]);
        }
        float phA[8], phB[8];
#pragma unroll
        for (int j = 0; j < 8; ++j) {
            h16x8 wv = *reinterpret_cast<const h16x8*>(&w1h[j * DIM + dbase]);
            float a = 0.f, b = 0.f;
#pragma unroll
            for (int i = 0; i < 4; ++i) {
                h16x2 wp; wp.x = wv[2 * i]; wp.y = wv[2 * i + 1];
                a = __builtin_amdgcn_fdot2(xhA[i], wp, a, false);
                b = __builtin_amdgcn_fdot2(xhB[i], wp, b, false);
            }
            phA[j] = a; phB[j] = b;
        }

        // ---- reductions: 6 independent trees interleave ----
        const float swA = wave_sum(sA);
        const float qwA = wave_sum(qA);
        const float swB = wave_sum(sB);
        const float qwB = wave_sum(qB);
        const float HwA = reduce8(phA, lj);
        const float HwB = reduce8(phB, lj);

        const float muA  = swA * (1.0f / DIM);
        const float varA = qwA * (1.0f / DIM) - muA * muA;
        const float rsA  = rsqrtf(varA + LN_EPS);
        const float muB  = swB * (1.0f / DIM);
        const float varB = qwB * (1.0f / DIM) - muB * muB;
        const float rsB  = rsqrtf(varB + LN_EPS);

        const float hA = gelu_fast(fmaf(rsA, fmaf(-muA, W1s, HwA), b1e));
        const float hB = gelu_fast(fmaf(rsB, fmaf(-muB, W1s, HwB), b1e));

        // ---- broadcast H via readlane ----
        float hvA[8], hvB[8];
#pragma unroll
        for (int j = 0; j < 8; ++j) {
            hvA[j] = readlanef(hA, j);
            hvB[j] = readlanef(hB, j);
        }
        h16x2 hpA[4], hpB[4];
#pragma unroll
        for (int i = 0; i < 4; ++i) {
            hpA[i] = __builtin_amdgcn_cvt_pkrtz(hvA[2 * i], hvA[2 * i + 1]);
            hpB[i] = __builtin_amdgcn_cvt_pkrtz(hvB[2 * i], hvB[2 * i + 1]);
        }

        // ---- stage 2 (one w2 ds_read feeds both rows) ----
        f32x4 oA0, oA1, oB0, oB1;
#pragma unroll
        for (int t = 0; t < 8; ++t) {
            h16x8 wv = *reinterpret_cast<const h16x8*>(
                &w2h[(lane * 8 + (t ^ lj)) * 8]);
            float oa = b2r[t], ob = b2r[t];
#pragma unroll
            for (int i = 0; i < 4; ++i) {
                h16x2 wp; wp.x = wv[2 * i]; wp.y = wv[2 * i + 1];
                oa = __builtin_amdgcn_fdot2(hpA[i], wp, oa, false);
                ob = __builtin_amdgcn_fdot2(hpB[i], wp, ob, false);
            }
            float va = gelu_fast(oa) + xvA[t];
            float vb = gelu_fast(ob) + xvB[t];
            if (t < 4) { oA0[t] = va; oB0[t] = vb; }
            else       { oA1[t - 4] = va; oB1[t - 4] = vb; }
        }

        // ---- plain cached stores (nt caused HBM write amplification) ----
        {
            f32x4* po = reinterpret_cast<f32x4*>(out + (size_t)r * DIM + dbase);
            po[0] = oA0; po[1] = oA1;
        }
        {
            f32x4* po = reinterpret_cast<f32x4*>(out + (size_t)(r + 1) * DIM + dbase);
            po[0] = oB0; po[1] = oB1;
        }

#pragma unroll
        for (int k = 0; k < 8; ++k) { xvA[k] = xnA[k]; xvB[k] = xnB[k]; }
    }

    // ---- odd tail row ----
    if (r < r1) {
        float s = 0.f, q = 0.f;
#pragma unroll
        for (int k = 0; k < 8; ++k) { s += xvA[k]; q = fmaf(xvA[k], xvA[k], q); }
        h16x2 xh[4];
#pragma unroll
        for (int i = 0; i < 4; ++i)
            xh[i] = __builtin_amdgcn_cvt_pkrtz(xvA[2 * i], xvA[2 * i + 1]);
        float ph[8];
#pragma unroll
        for (int j = 0; j < 8; ++j) {
            h16x8 wv = *reinterpret_cast<const h16x8*>(&w1h[j * DIM + dbase]);
            float a = 0.f;
#pragma unroll
            for (int i = 0; i < 4; ++i) {
                h16x2 wp; wp.x = wv[2 * i]; wp.y = wv[2 * i + 1];
                a = __builtin_amdgcn_fdot2(xh[i], wp, a, false);
            }
            ph[j] = a;
        }
        const float sw = wave_sum(s);
        const float qw = wave_sum(q);
        const float Hw = reduce8(ph, lj);
        const float mu  = sw * (1.0f / DIM);
        const float var = qw * (1.0f / DIM) - mu * mu;
        const float rs  = rsqrtf(var + LN_EPS);
        const float h   = gelu_fast(fmaf(rs, fmaf(-mu, W1s, Hw), b1e));
        float hv[8];
#pragma unroll
        for (int j = 0; j < 8; ++j) hv[j] = readlanef(h, j);
        h16x2 hp[4];
#pragma unroll
        for (int i = 0; i < 4; ++i)
            hp[i] = __builtin_amdgcn_cvt_pkrtz(hv[2 * i], hv[2 * i + 1]);
        f32x4 o0, o1;
#pragma unroll
        for (int t = 0; t < 8; ++t) {
            h16x8 wv = *reinterpret_cast<const h16x8*>(
                &w2h[(lane * 8 + (t ^ lj)) * 8]);
            float o = b2r[t];
#pragma unroll
            for (int i = 0; i < 4; ++i) {
                h16x2 wp; wp.x = wv[2 * i]; wp.y = wv[2 * i + 1];
                o = __builtin_amdgcn_fdot2(hp[i], wp, o, false);
            }
            float val = gelu_fast(o) + xvA[t];
            if (t < 4) o0[t] = val; else o1[t - 4] = val;
        }
        f32x4* po = reinterpret_cast<f32x4*>(out + (size_t)r * DIM + dbase);
        po[0] = o0; po[1] = o1;
    }
}

extern "C" void kernel_launch(void* const* d_in, const int* in_sizes, int n_in,
                              void* d_out, int out_size, void* d_ws, size_t ws_size,
                              hipStream_t stream) {
    const float* x     = (const float*)d_in[0];
    const float* w1    = (const float*)d_in[1];
    const float* b1    = (const float*)d_in[2];
    const float* w2    = (const float*)d_in[3];
    const float* b2    = (const float*)d_in[4];
    const float* gamma = (const float*)d_in[5];
    const float* beta  = (const float*)d_in[6];
    float* out = (float*)d_out;

    const int nrows  = in_sizes[0] / DIM;         // 131072
    const int blocks = 2048;                      // 4 waves each = 8192 waves
    const int total_waves = blocks * 4;
    const int rows_per_wave = (nrows + total_waves - 1) / total_waves;  // 16

    mlp_fused_kernel<<<blocks, 256, 0, stream>>>(
        x, w1, b1, w2, b2, gamma, beta, out, nrows, rows_per_wave);
}

// Round 12
// 141.664 us; speedup vs baseline: 1.2367x; 1.2367x over previous
//
#include <hip/hip_runtime.h>
#include <math.h>

#define DIM 512
#define HID 8
#define LN_EPS 1e-5f

typedef float  f32x4 __attribute__((ext_vector_type(4)));
typedef __fp16 h16x2 __attribute__((ext_vector_type(2)));
typedef __fp16 h16x8 __attribute__((ext_vector_type(8)));

// ---- DPP cross-lane helpers ----
#define DPP_XOR1 0xB1   // quad_perm [1,0,3,2] : xor1
#define DPP_XOR2 0x4E   // quad_perm [2,3,0,1] : xor2
#define DPP_HM   0x141  // row_half_mirror: ==xor4 once 4-uniform
#define DPP_ROR8 0x128  // (i+8)&15 == i^8 : xor8 within 16

template <int CTRL>
__device__ __forceinline__ float dpp_movf(float v) {
    int r = __builtin_amdgcn_update_dpp(0, __builtin_bit_cast(int, v),
                                        CTRL, 0xF, 0xF, true);
    return __builtin_bit_cast(float, r);
}
template <int CTRL>
__device__ __forceinline__ float dpp_addf(float v) {
    return v + dpp_movf<CTRL>(v);
}
__device__ __forceinline__ float readlanef(float v, int lane) {
    return __builtin_bit_cast(float,
        __builtin_amdgcn_readlane(__builtin_bit_cast(int, v), lane));
}

// tanh-GELU via hardware exp2/rcp (abs err ~1e-3 vs exact; threshold 0.166)
__device__ __forceinline__ float gelu_fast(float v) {
    const float C = 0.044715f;
    const float K = 2.30258819f; // 2*0.7978845608*log2(e)
    float v2 = v * v;
    float t  = v * fmaf(C, v2, 1.0f);
    float e  = __builtin_amdgcn_exp2f(K * t);
    float r  = __builtin_amdgcn_rcpf(e + 1.0f);
    return fmaf(-v, r, v);
}

// full wave sum of a scalar (zero LDS)
__device__ __forceinline__ float wave_sum(float v) {
    v = dpp_addf<DPP_XOR1>(v);
    v = dpp_addf<DPP_XOR2>(v);
    v = dpp_addf<DPP_HM>(v);
    v = dpp_addf<DPP_ROR8>(v);
    return (readlanef(v, 0) + readlanef(v, 16))
         + (readlanef(v, 32) + readlanef(v, 48));
}

// reduce 8 partials; every lane ends with wave-complete sum of partial[lane&7]
__device__ __forceinline__ float reduce8(float ph[8], int lj) {
#pragma unroll
    for (int j = 0; j < 8; ++j) ph[j] = dpp_addf<DPP_XOR1>(ph[j]);
#pragma unroll
    for (int j = 0; j < 8; ++j) ph[j] = dpp_addf<DPP_XOR2>(ph[j]);
#pragma unroll
    for (int j = 0; j < 8; ++j) ph[j] = dpp_addf<DPP_HM>(ph[j]);
    float sel = ph[0];
    sel = (lj == 1) ? ph[1] : sel;
    sel = (lj == 2) ? ph[2] : sel;
    sel = (lj == 3) ? ph[3] : sel;
    sel = (lj == 4) ? ph[4] : sel;
    sel = (lj == 5) ? ph[5] : sel;
    sel = (lj == 6) ? ph[6] : sel;
    sel = (lj == 7) ? ph[7] : sel;
    sel = dpp_addf<DPP_ROR8>(sel);
    sel += __shfl_xor(sel, 16, 64);
    sel += __shfl_xor(sel, 32, 64);
    return sel;
}

__device__ __forceinline__ void load8(float* dst, const float* __restrict__ src) {
    const f32x4* p = reinterpret_cast<const f32x4*>(src);
    f32x4 a = p[0];
    f32x4 b = p[1];
    dst[0] = a.x; dst[1] = a.y; dst[2] = a.z; dst[3] = a.w;
    dst[4] = b.x; dst[5] = b.y; dst[6] = b.z; dst[7] = b.w;
}

// Weights in EXPLICIT LDS (fp16, LN-folded), shared block-wide.
// waves_per_eu(4,4): 128-VGPR budget so the 2-row-unrolled loop state (~95
// VGPR) fits with ZERO scratch spill. R11 (no attribute) was capped at 68
// VGPR -> per-iteration scratch spills -> 250 MB of HBM write amplification.
__global__ __launch_bounds__(256)
__attribute__((amdgpu_waves_per_eu(4, 4)))
void mlp_fused_kernel(const float* __restrict__ x,
                      const float* __restrict__ w1,
                      const float* __restrict__ b1,
                      const float* __restrict__ w2,
                      const float* __restrict__ b2,
                      const float* __restrict__ gamma,
                      const float* __restrict__ beta,
                      float* __restrict__ out,
                      int nrows, int rows_per_wave) {
    __shared__ __fp16 w1h[8 * DIM];    // [j][d] fp16, w1*gamma   (8 KB)
    __shared__ __fp16 w2h[DIM * HID];  // row-swizzled             (8 KB)

    const int tid  = threadIdx.x;
    const int lane = tid & 63;
    const int wav  = tid >> 6;
    const int lj   = lane & 7;
    const int dbase = lane * 8;

    // ================= staging (once per block) =================
    {
        const int j  = tid >> 5;
        const int d0 = (tid & 31) * 16;
        const float* wsrc = w1 + j * DIM + d0;
        const float* gsrc = gamma + d0;
        h16x8 p0, p1;
#pragma unroll
        for (int i = 0; i < 4; ++i) {
            float a = wsrc[2 * i]     * gsrc[2 * i];
            float b = wsrc[2 * i + 1] * gsrc[2 * i + 1];
            h16x2 p = __builtin_amdgcn_cvt_pkrtz(a, b);
            p0[2 * i] = p.x; p0[2 * i + 1] = p.y;
        }
#pragma unroll
        for (int i = 0; i < 4; ++i) {
            float a = wsrc[8 + 2 * i]     * gsrc[8 + 2 * i];
            float b = wsrc[8 + 2 * i + 1] * gsrc[8 + 2 * i + 1];
            h16x2 p = __builtin_amdgcn_cvt_pkrtz(a, b);
            p1[2 * i] = p.x; p1[2 * i + 1] = p.y;
        }
        *reinterpret_cast<h16x8*>(&w1h[j * DIM + d0])     = p0;
        *reinterpret_cast<h16x8*>(&w1h[j * DIM + d0 + 8]) = p1;

        // w2h: row d -> swizzled 16B-unit u(d) = (d>>3)*8 + ((d&7)^((d>>3)&7))
        // reader lane L, instr t reads unit L*8 + (t^(L&7)) == row L*8+t,
        // conflict-free across the wave.
#pragma unroll
        for (int rr = 0; rr < 2; ++rr) {
            const int d = tid + rr * 256;
            const float* src = w2 + (size_t)d * HID;
            f32x4 a = *reinterpret_cast<const f32x4*>(src);
            f32x4 b = *reinterpret_cast<const f32x4*>(src + 4);
            h16x8 pk;
            h16x2 q0 = __builtin_amdgcn_cvt_pkrtz(a.x, a.y);
            h16x2 q1 = __builtin_amdgcn_cvt_pkrtz(a.z, a.w);
            h16x2 q2 = __builtin_amdgcn_cvt_pkrtz(b.x, b.y);
            h16x2 q3 = __builtin_amdgcn_cvt_pkrtz(b.z, b.w);
            pk[0] = q0.x; pk[1] = q0.y; pk[2] = q1.x; pk[3] = q1.y;
            pk[4] = q2.x; pk[5] = q2.y; pk[6] = q3.x; pk[7] = q3.y;
            const int u = ((d >> 3) << 3) + ((d & 7) ^ ((d >> 3) & 7));
            *reinterpret_cast<h16x8*>(&w2h[u * 8]) = pk;
        }
    }
    __syncthreads();

    // ================= per-wave startup constants =================
    float w1sp[8];
#pragma unroll
    for (int j = 0; j < 8; ++j) {
        h16x8 wv = *reinterpret_cast<const h16x8*>(&w1h[j * DIM + dbase]);
        float a = 0.f;
#pragma unroll
        for (int i = 0; i < 8; ++i) a += (float)wv[i];
        w1sp[j] = a;
    }
    const float W1s = reduce8(w1sp, lj);   // Sum_d fp16(w1*gamma)[lj,d] (rounded)

    float bt[8];
    load8(bt, beta + dbase);
    float c1p[8];
#pragma unroll
    for (int j = 0; j < 8; ++j) {
        float raw[8];
        load8(raw, w1 + j * DIM + dbase);
        float a = 0.f;
#pragma unroll
        for (int k = 0; k < 8; ++k) a = fmaf(bt[k], raw[k], a);
        c1p[j] = a;
    }
    const float b1e = b1[lj] + reduce8(c1p, lj);

    float b2r[8];
    load8(b2r, b2 + dbase);

    // ================= row-pair loop =================
    const int wgid = blockIdx.x * 4 + wav;
    const int r0 = wgid * rows_per_wave;
    if (r0 >= nrows) return;
    int r1 = r0 + rows_per_wave;
    if (r1 > nrows) r1 = nrows;

    float xvA[8], xvB[8];
    load8(xvA, x + (size_t)r0 * DIM + dbase);
    {
        const int rb = (r0 + 1 < r1) ? r0 + 1 : r0;
        load8(xvB, x + (size_t)rb * DIM + dbase);
    }

    int r = r0;
    for (; r + 1 < r1; r += 2) {
        float xnA[8], xnB[8];
        const int ra2 = (r + 2 < r1) ? r + 2 : r1 - 1;
        const int rb2 = (r + 3 < r1) ? r + 3 : r1 - 1;
        load8(xnA, x + (size_t)ra2 * DIM + dbase);
        load8(xnB, x + (size_t)rb2 * DIM + dbase);

        // ---- LN stats ----
        float sA = 0.f, qA = 0.f, sB = 0.f, qB = 0.f;
#pragma unroll
        for (int k = 0; k < 8; ++k) {
            sA += xvA[k]; qA = fmaf(xvA[k], xvA[k], qA);
            sB += xvB[k]; qB = fmaf(xvB[k], xvB[k], qB);
        }

        // ---- pack x; stage-1 partials (one w1 ds_read feeds both rows) ----
        h16x2 xhA[4], xhB[4];
#pragma unroll
        for (int i = 0; i < 4; ++i) {
            xhA[i] = __builtin_amdgcn_cvt_pkrtz(xvA[2 * i], xvA[2 * i + 1]);
            xhB[i] = __builtin_amdgcn_cvt_pkrtz(xvB[2 * i], xvB[2 * i + 1]);
        }
        float phA[8], phB[8];
#pragma unroll
        for (int j = 0; j < 8; ++j) {
            h16x8 wv = *reinterpret_cast<const h16x8*>(&w1h[j * DIM + dbase]);
            float a = 0.f, b = 0.f;
#pragma unroll
            for (int i = 0; i < 4; ++i) {
                h16x2 wp; wp.x = wv[2 * i]; wp.y = wv[2 * i + 1];
                a = __builtin_amdgcn_fdot2(xhA[i], wp, a, false);
                b = __builtin_amdgcn_fdot2(xhB[i], wp, b, false);
            }
            phA[j] = a; phB[j] = b;
        }

        // ---- reductions: 6 independent trees interleave ----
        const float swA = wave_sum(sA);
        const float qwA = wave_sum(qA);
        const float swB = wave_sum(sB);
        const float qwB = wave_sum(qB);
        const float HwA = reduce8(phA, lj);
        const float HwB = reduce8(phB, lj);

        const float muA  = swA * (1.0f / DIM);
        const float varA = qwA * (1.0f / DIM) - muA * muA;
        const float rsA  = rsqrtf(varA + LN_EPS);
        const float muB  = swB * (1.0f / DIM);
        const float varB = qwB * (1.0f / DIM) - muB * muB;
        const float rsB  = rsqrtf(varB + LN_EPS);

        const float hA = gelu_fast(fmaf(rsA, fmaf(-muA, W1s, HwA), b1e));
        const float hB = gelu_fast(fmaf(rsB, fmaf(-muB, W1s, HwB), b1e));

        // ---- broadcast H via readlane ----
        float hvA[8], hvB[8];
#pragma unroll
        for (int j = 0; j < 8; ++j) {
            hvA[j] = readlanef(hA, j);
            hvB[j] = readlanef(hB, j);
        }
        h16x2 hpA[4], hpB[4];
#pragma unroll
        for (int i = 0; i < 4; ++i) {
            hpA[i] = __builtin_amdgcn_cvt_pkrtz(hvA[2 * i], hvA[2 * i + 1]);
            hpB[i] = __builtin_amdgcn_cvt_pkrtz(hvB[2 * i], hvB[2 * i + 1]);
        }

        // ---- stage 2 (one w2 ds_read feeds both rows) ----
        f32x4 oA0, oA1, oB0, oB1;
#pragma unroll
        for (int t = 0; t < 8; ++t) {
            h16x8 wv = *reinterpret_cast<const h16x8*>(
                &w2h[(lane * 8 + (t ^ lj)) * 8]);
            float oa = b2r[t], ob = b2r[t];
#pragma unroll
            for (int i = 0; i < 4; ++i) {
                h16x2 wp; wp.x = wv[2 * i]; wp.y = wv[2 * i + 1];
                oa = __builtin_amdgcn_fdot2(hpA[i], wp, oa, false);
                ob = __builtin_amdgcn_fdot2(hpB[i], wp, ob, false);
            }
            float va = gelu_fast(oa) + xvA[t];
            float vb = gelu_fast(ob) + xvB[t];
            if (t < 4) { oA0[t] = va; oB0[t] = vb; }
            else       { oA1[t - 4] = va; oB1[t - 4] = vb; }
        }

        // ---- plain cached stores ----
        {
            f32x4* po = reinterpret_cast<f32x4*>(out + (size_t)r * DIM + dbase);
            po[0] = oA0; po[1] = oA1;
        }
        {
            f32x4* po = reinterpret_cast<f32x4*>(out + (size_t)(r + 1) * DIM + dbase);
            po[0] = oB0; po[1] = oB1;
        }

#pragma unroll
        for (int k = 0; k < 8; ++k) { xvA[k] = xnA[k]; xvB[k] = xnB[k]; }
    }

    // ---- odd tail row ----
    if (r < r1) {
        float s = 0.f, q = 0.f;
#pragma unroll
        for (int k = 0; k < 8; ++k) { s += xvA[k]; q = fmaf(xvA[k], xvA[k], q); }
        h16x2 xh[4];
#pragma unroll
        for (int i = 0; i < 4; ++i)
            xh[i] = __builtin_amdgcn_cvt_pkrtz(xvA[2 * i], xvA[2 * i + 1]);
        float ph[8];
#pragma unroll
        for (int j = 0; j < 8; ++j) {
            h16x8 wv = *reinterpret_cast<const h16x8*>(&w1h[j * DIM + dbase]);
            float a = 0.f;
#pragma unroll
            for (int i = 0; i < 4; ++i) {
                h16x2 wp; wp.x = wv[2 * i]; wp.y = wv[2 * i + 1];
                a = __builtin_amdgcn_fdot2(xh[i], wp, a, false);
            }
            ph[j] = a;
        }
        const float sw = wave_sum(s);
        const float qw = wave_sum(q);
        const float Hw = reduce8(ph, lj);
        const float mu  = sw * (1.0f / DIM);
        const float var = qw * (1.0f / DIM) - mu * mu;
        const float rs  = rsqrtf(var + LN_EPS);
        const float h   = gelu_fast(fmaf(rs, fmaf(-mu, W1s, Hw), b1e));
        float hv[8];
#pragma unroll
        for (int j = 0; j < 8; ++j) hv[j] = readlanef(h, j);
        h16x2 hp[4];
#pragma unroll
        for (int i = 0; i < 4; ++i)
            hp[i] = __builtin_amdgcn_cvt_pkrtz(hv[2 * i], hv[2 * i + 1]);
        f32x4 o0, o1;
#pragma unroll
        for (int t = 0; t < 8; ++t) {
            h16x8 wv = *reinterpret_cast<const h16x8*>(
                &w2h[(lane * 8 + (t ^ lj)) * 8]);
            float o = b2r[t];
#pragma unroll
            for (int i = 0; i < 4; ++i) {
                h16x2 wp; wp.x = wv[2 * i]; wp.y = wv[2 * i + 1];
                o = __builtin_amdgcn_fdot2(hp[i], wp, o, false);
            }
            float val = gelu_fast(o) + xvA[t];
            if (t < 4) o0[t] = val; else o1[t - 4] = val;
        }
        f32x4* po = reinterpret_cast<f32x4*>(out + (size_t)r * DIM + dbase);
        po[0] = o0; po[1] = o1;
    }
}

extern "C" void kernel_launch(void* const* d_in, const int* in_sizes, int n_in,
                              void* d_out, int out_size, void* d_ws, size_t ws_size,
                              hipStream_t stream) {
    const float* x     = (const float*)d_in[0];
    const float* w1    = (const float*)d_in[1];
    const float* b1    = (const float*)d_in[2];
    const float* w2    = (const float*)d_in[3];
    const float* b2    = (const float*)d_in[4];
    const float* gamma = (const float*)d_in[5];
    const float* beta  = (const float*)d_in[6];
    float* out = (float*)d_out;

    const int nrows  = in_sizes[0] / DIM;         // 131072
    const int blocks = 2048;                      // 4 waves each = 8192 waves
    const int total_waves = blocks * 4;
    const int rows_per_wave = (nrows + total_waves - 1) / total_waves;  // 16

    mlp_fused_kernel<<<blocks, 256, 0, stream>>>(
        x, w1, b1, w2, b2, gamma, beta, out, nrows, rows_per_wave);
}